// Round 1
// baseline (3607.446 us; speedup 1.0000x reference)
//
#include <hip/hip_runtime.h>
#include <math.h>

// RITS recurrent imputation model, MI355X baseline (fp32, correctness-first).
//
// Sizes (fixed by the reference):
#define T_LEN 252
#define FEAT  21
#define HID   128
#define BTOT  4096
#define BT    16            // batch rows per block
#define NB    (BTOT / BT)   // 256 blocks = 1 per CU
#define NTHR  512           // 8 waves per block

// ws layout (floats):
//   whh4  : [128][128][4]  = 65536   (W_hh transposed+gate-interleaved)
//   wih4  : [42][128][4]   = 21504   (W_ih transposed+gate-interleaved)
//   wsnum : [252][256]     = 64512   (per-(t,block) x_loss numerator partial)
//   wsden : [252][256]     = 64512
//   wsynum: [256]
//   wsyden: [256]
#define WS_WHH4   0
#define WS_WIH4   65536
#define WS_NUM    87040
#define WS_DEN    151552
#define WS_YNUM   216064
#define WS_YDEN   216320

__device__ __forceinline__ float sigmoid_f(float x) {
    return 1.0f / (1.0f + __expf(-x));
}
__device__ __forceinline__ float tanh_f(float x) {
    // 2*sigmoid(2x)-1 : no NaN at extremes (exp->inf gives -1, exp->0 gives 1)
    return 2.0f / (1.0f + __expf(-2.0f * x)) - 1.0f;
}

// ---- pre-pass: transpose weights into [k][jh][gate] float4-friendly layout ----
__global__ __launch_bounds__(256) void rits_pre(
    const float* __restrict__ W_ih, const float* __restrict__ W_hh,
    float* __restrict__ wih4, float* __restrict__ whh4)
{
    int idx = blockIdx.x * blockDim.x + threadIdx.x;
    if (idx < HID * HID * 4) {
        int g = idx & 3, jh = (idx >> 2) & (HID - 1), k = idx >> 9;
        whh4[idx] = W_hh[(g * HID + jh) * HID + k];
    } else {
        int i2 = idx - HID * HID * 4;
        if (i2 < (2 * FEAT) * HID * 4) {
            int g = i2 & 3, jh = (i2 >> 2) & (HID - 1), k = i2 >> 9;
            wih4[i2] = W_ih[(g * HID + jh) * (2 * FEAT) + k];
        }
    }
}

#define GFMA(ACC, HV, W) \
    ACC.x += (HV) * (W).x; ACC.y += (HV) * (W).y; \
    ACC.z += (HV) * (W).z; ACC.w += (HV) * (W).w;

// ---- main recurrent kernel: 256 blocks x 512 threads, whole T loop inside ----
__global__ __launch_bounds__(NTHR) void rits_main(
    const float* __restrict__ values, const float* __restrict__ masks,
    const float* __restrict__ deltas,
    const float* __restrict__ labels, const float* __restrict__ is_train,
    const float* __restrict__ W_decay, const float* __restrict__ b_decay,
    const float* __restrict__ W_reg, const float* __restrict__ b_reg,
    const float* __restrict__ b_ih, const float* __restrict__ b_hh,
    const float* __restrict__ W_out, const float* __restrict__ b_out,
    const float* __restrict__ whh4, const float* __restrict__ wih4,
    float* __restrict__ out_yh,     // d_out + 1            [BTOT]
    float* __restrict__ out_imp,    // d_out + 1 + BTOT     [BTOT][T][FEAT]
    float* __restrict__ wsnum, float* __restrict__ wsden,
    float* __restrict__ wsynum, float* __restrict__ wsyden)
{
    const int tid   = threadIdx.x;
    const int blk   = blockIdx.x;
    const int bbase = blk * BT;

    __shared__ float h_s[BT][HID + 4];     // stride 132: 16B-aligned rows, banks spread
    __shared__ float wdec_s[HID * FEAT];   // [jh][f]
    __shared__ float bdec_s[HID];
    __shared__ float wregT_s[HID * FEAT];  // [jh][f]  (transposed from W_reg[f][jh])
    __shared__ float breg_s[FEAT];
    __shared__ float bsum_s[HID * 4];      // [jh][g] = b_ih + b_hh
    __shared__ float x_s[BT][FEAT + 1];
    __shared__ float d_s[BT][FEAT + 1];
    __shared__ float im_s[BT][2 * FEAT + 2]; // [r][0:21]=x_c, [r][21:42]=m
    __shared__ float scrn_s[NTHR / 64], scrd_s[NTHR / 64];

    // -------- load block-invariant weights --------
    for (int i = tid; i < HID * FEAT; i += NTHR) wdec_s[i] = W_decay[i];
    for (int i = tid; i < HID * FEAT; i += NTHR) {
        int jh = i / FEAT, f = i - jh * FEAT;
        wregT_s[i] = W_reg[f * HID + jh];
    }
    for (int i = tid; i < HID; i += NTHR) bdec_s[i] = b_decay[i];
    for (int i = tid; i < FEAT; i += NTHR) breg_s[i] = b_reg[i];
    for (int i = tid; i < 4 * HID; i += NTHR) {
        int jh = i >> 2, g = i & 3;
        bsum_s[i] = b_ih[g * HID + jh] + b_hh[g * HID + jh];
    }
    for (int i = tid; i < BT * (HID + 4); i += NTHR) ((float*)h_s)[i] = 0.0f;
    __syncthreads();

    const int jh = tid & (HID - 1);     // 0..127
    const int r0 = (tid >> 7) * 4;      // 0,4,8,12
    float c0 = 0.f, c1 = 0.f, c2 = 0.f, c3 = 0.f;   // cell state lives in regs

    for (int t = 0; t < T_LEN; ++t) {
        // -------- load x, m, d for this timestep --------
        if (tid < BT * FEAT) {
            int r = tid / FEAT, f = tid - r * FEAT;
            int off = (bbase + r) * (T_LEN * FEAT) + t * FEAT + f;
            x_s[r][f] = values[off];
            im_s[r][FEAT + f] = masks[off];
            d_s[r][f] = deltas[off];
        }
        __syncthreads();

        // -------- phase A: gamma decay, h *= exp(-relu(d @ Wd^T + bd)) --------
        {
            float bd = bdec_s[jh];
            #pragma unroll
            for (int i = 0; i < 4; ++i) {
                int r = r0 + i;
                float acc = bd;
                #pragma unroll
                for (int f = 0; f < FEAT; ++f) acc += wdec_s[jh * FEAT + f] * d_s[r][f];
                float gamma = __expf(-fmaxf(acc, 0.0f));
                h_s[r][jh] *= gamma;
            }
        }
        __syncthreads();

        // -------- phase B: x_h, x_c, imputation write, loss partials --------
        float nd_num = 0.0f, nd_den = 0.0f;
        if (tid < BT * FEAT) {
            int r = tid / FEAT, f = tid - r * FEAT;
            float acc = breg_s[f];
            for (int k = 0; k < HID; ++k) acc += wregT_s[k * FEAT + f] * h_s[r][k];
            float xv = x_s[r][f];
            float mv = im_s[r][FEAT + f];
            float xc = mv * xv + (1.0f - mv) * acc;
            im_s[r][f] = xc;
            out_imp[((bbase + r) * T_LEN + t) * FEAT + f] = xc;
            nd_num = fabsf(xv - acc) * mv;
            nd_den = mv;
        }
        #pragma unroll
        for (int s = 32; s > 0; s >>= 1) {
            nd_num += __shfl_down(nd_num, s);
            nd_den += __shfl_down(nd_den, s);
        }
        if ((tid & 63) == 0) { scrn_s[tid >> 6] = nd_num; scrd_s[tid >> 6] = nd_den; }
        __syncthreads();

        if (tid == 0) {
            float n = 0.f, d = 0.f;
            #pragma unroll
            for (int w = 0; w < NTHR / 64; ++w) { n += scrn_s[w]; d += scrd_s[w]; }
            wsnum[t * NB + blk] = n;
            wsden[t * NB + blk] = d;
        }

        // -------- phase C: gates = [x_c,m] @ Wih^T + h @ Whh^T + b --------
        float4 bs = *(const float4*)&bsum_s[jh * 4];
        float4 acc0 = bs, acc1 = bs, acc2 = bs, acc3 = bs;

        #define WHH_STEP(HX0, HX1, HX2, HX3, KOFF) { \
            float4 w = *(const float4*)&whh4[(((kk + KOFF) * HID) + jh) * 4]; \
            GFMA(acc0, HX0, w); GFMA(acc1, HX1, w); \
            GFMA(acc2, HX2, w); GFMA(acc3, HX3, w); }

        for (int kk = 0; kk < HID; kk += 4) {
            float4 h0 = *(const float4*)&h_s[r0 + 0][kk];
            float4 h1 = *(const float4*)&h_s[r0 + 1][kk];
            float4 h2 = *(const float4*)&h_s[r0 + 2][kk];
            float4 h3 = *(const float4*)&h_s[r0 + 3][kk];
            WHH_STEP(h0.x, h1.x, h2.x, h3.x, 0)
            WHH_STEP(h0.y, h1.y, h2.y, h3.y, 1)
            WHH_STEP(h0.z, h1.z, h2.z, h3.z, 2)
            WHH_STEP(h0.w, h1.w, h2.w, h3.w, 3)
        }
        #pragma unroll
        for (int k2 = 0; k2 < 2 * FEAT; ++k2) {
            float4 w = *(const float4*)&wih4[((k2 * HID) + jh) * 4];
            float v0 = im_s[r0 + 0][k2];
            float v1 = im_s[r0 + 1][k2];
            float v2 = im_s[r0 + 2][k2];
            float v3 = im_s[r0 + 3][k2];
            GFMA(acc0, v0, w); GFMA(acc1, v1, w);
            GFMA(acc2, v2, w); GFMA(acc3, v3, w);
        }
        __syncthreads();   // all reads of old h done before overwriting

        // -------- phase D: LSTM update, write new h --------
        {
            float ig, fg, gg, og;
            ig = sigmoid_f(acc0.x); fg = sigmoid_f(acc0.y);
            gg = tanh_f(acc0.z);    og = sigmoid_f(acc0.w);
            c0 = fg * c0 + ig * gg; h_s[r0 + 0][jh] = og * tanh_f(c0);
            ig = sigmoid_f(acc1.x); fg = sigmoid_f(acc1.y);
            gg = tanh_f(acc1.z);    og = sigmoid_f(acc1.w);
            c1 = fg * c1 + ig * gg; h_s[r0 + 1][jh] = og * tanh_f(c1);
            ig = sigmoid_f(acc2.x); fg = sigmoid_f(acc2.y);
            gg = tanh_f(acc2.z);    og = sigmoid_f(acc2.w);
            c2 = fg * c2 + ig * gg; h_s[r0 + 2][jh] = og * tanh_f(c2);
            ig = sigmoid_f(acc3.x); fg = sigmoid_f(acc3.y);
            gg = tanh_f(acc3.z);    og = sigmoid_f(acc3.w);
            c3 = fg * c3 + ig * gg; h_s[r0 + 3][jh] = og * tanh_f(c3);
        }
        __syncthreads();
    }

    // -------- epilogue: y_h and y_loss partials --------
    float yerr = 0.0f, ytr = 0.0f;
    if (tid < BT) {
        int r = tid;
        float acc = b_out[0];
        for (int k = 0; k < HID; ++k) acc += W_out[k] * h_s[r][k];
        out_yh[bbase + r] = acc;
        float it = is_train[bbase + r];
        float dv = acc - labels[bbase + r];
        yerr = dv * dv * it;
        ytr  = it;
    }
    #pragma unroll
    for (int s = 8; s > 0; s >>= 1) {
        yerr += __shfl_down(yerr, s);
        ytr  += __shfl_down(ytr, s);
    }
    if (tid == 0) { wsynum[blk] = yerr; wsyden[blk] = ytr; }
}

// ---- final tiny reduction: loss = sum_t num_t/(den_t+eps) + y_loss ----
__global__ __launch_bounds__(256) void rits_final(
    const float* __restrict__ wsnum, const float* __restrict__ wsden,
    const float* __restrict__ wsynum, const float* __restrict__ wsyden,
    float* __restrict__ d_out)
{
    __shared__ float sx[256], sy[256], sz[256];
    int tid = threadIdx.x;
    float v = 0.0f;
    if (tid < T_LEN) {
        float n = 0.f, d = 0.f;
        for (int b = 0; b < NB; ++b) { n += wsnum[tid * NB + b]; d += wsden[tid * NB + b]; }
        v = n / (d + 1e-5f);
    }
    sx[tid] = v;
    sy[tid] = wsynum[tid];
    sz[tid] = wsyden[tid];
    __syncthreads();
    for (int s = 128; s > 0; s >>= 1) {
        if (tid < s) { sx[tid] += sx[tid + s]; sy[tid] += sy[tid + s]; sz[tid] += sz[tid + s]; }
        __syncthreads();
    }
    if (tid == 0) d_out[0] = sx[0] + sy[0] / (sz[0] + 1e-5f);
}

extern "C" void kernel_launch(void* const* d_in, const int* in_sizes, int n_in,
                              void* d_out, int out_size, void* d_ws, size_t ws_size,
                              hipStream_t stream)
{
    const float* values    = (const float*)d_in[0];
    const float* masks     = (const float*)d_in[1];
    const float* deltas    = (const float*)d_in[2];
    // d_in[3] = evals, d_in[4] = eval_masks : unused by the reference
    const float* labels    = (const float*)d_in[5];
    const float* is_train  = (const float*)d_in[6];
    const float* W_decay   = (const float*)d_in[7];
    const float* b_decay   = (const float*)d_in[8];
    const float* W_reg     = (const float*)d_in[9];
    const float* b_reg     = (const float*)d_in[10];
    const float* W_ih      = (const float*)d_in[11];
    const float* W_hh      = (const float*)d_in[12];
    const float* b_ih      = (const float*)d_in[13];
    const float* b_hh      = (const float*)d_in[14];
    const float* W_out     = (const float*)d_in[15];
    const float* b_out     = (const float*)d_in[16];

    float* ws     = (float*)d_ws;
    float* whh4   = ws + WS_WHH4;
    float* wih4   = ws + WS_WIH4;
    float* wsnum  = ws + WS_NUM;
    float* wsden  = ws + WS_DEN;
    float* wsynum = ws + WS_YNUM;
    float* wsyden = ws + WS_YDEN;

    float* out    = (float*)d_out;
    float* out_yh  = out + 1;
    float* out_imp = out + 1 + BTOT;

    int pre_total = HID * HID * 4 + (2 * FEAT) * HID * 4;   // 87040
    rits_pre<<<dim3((pre_total + 255) / 256), dim3(256), 0, stream>>>(W_ih, W_hh, wih4, whh4);

    rits_main<<<dim3(NB), dim3(NTHR), 0, stream>>>(
        values, masks, deltas, labels, is_train,
        W_decay, b_decay, W_reg, b_reg, b_ih, b_hh, W_out, b_out,
        whh4, wih4, out_yh, out_imp, wsnum, wsden, wsynum, wsyden);

    rits_final<<<dim3(1), dim3(256), 0, stream>>>(wsnum, wsden, wsynum, wsyden, out);
}

// Round 2
// 638.067 us; speedup vs baseline: 5.6537x; 5.6537x over previous
//
#include <hip/hip_runtime.h>
#include <math.h>

// RITS recurrent model, MFMA bf16 version.
// 256 blocks x 512 threads (8 waves). Each block owns 16 batch rows.
// Wave w owns hidden cols jh in [16w, 16w+16); lane layout per MFMA 16x16x32:
//   cidx = lane&15  -> (A) batch row / (B,D) column index
//   gidx = lane>>4  -> k-group (8 contiguous k per group)
//   D output: row r = 4*gidx + v (v = reg 0..3), col = cidx   [m89-verified]
// Gate columns are permuted so wave w's 4 B-tiles = 4 gates of its jh range;
// hence each lane holds i,f,g,o for its (r, jh) in regs -> c,h stay in VGPRs.

#define T_LEN 252
#define FEAT  21
#define HID   128
#define BTOT  4096
#define BT    16
#define NB    (BTOT / BT)   // 256
#define NTHR  512

// ws layout (floats)
#define WS_NUM    0
#define WS_DEN    (T_LEN * NB)
#define WS_YNUM   (2 * T_LEN * NB)
#define WS_YDEN   (2 * T_LEN * NB + NB)

typedef __attribute__((ext_vector_type(8))) short s16x8;
typedef __attribute__((ext_vector_type(4))) float f32x4;

#define MFMA16(A, B, C) __builtin_amdgcn_mfma_f32_16x16x32_bf16((A), (B), (C), 0, 0, 0)

__device__ __forceinline__ float sigmoid_f(float x) { return 1.0f / (1.0f + __expf(-x)); }
__device__ __forceinline__ float tanh_f(float x) {
    return 2.0f / (1.0f + __expf(-2.0f * x)) - 1.0f;
}
__device__ __forceinline__ unsigned short to_bf16(float x) {
    unsigned int u = __float_as_uint(x);
    unsigned int r = (u + 0x7FFFu + ((u >> 16) & 1u)) >> 16;   // RNE
    return (unsigned short)r;
}

__global__ __launch_bounds__(NTHR, 2) void rits_main(
    const float* __restrict__ values, const float* __restrict__ masks,
    const float* __restrict__ deltas,
    const float* __restrict__ labels, const float* __restrict__ is_train,
    const float* __restrict__ W_decay, const float* __restrict__ b_decay,
    const float* __restrict__ W_reg, const float* __restrict__ b_reg,
    const float* __restrict__ W_ih, const float* __restrict__ W_hh,
    const float* __restrict__ b_ih, const float* __restrict__ b_hh,
    const float* __restrict__ W_out, const float* __restrict__ b_out,
    float* __restrict__ out_yh,     // [BTOT]
    float* __restrict__ out_imp,    // [BTOT][T][FEAT]
    float* __restrict__ wsnum, float* __restrict__ wsden,
    float* __restrict__ wsynum, float* __restrict__ wsyden)
{
    const int tid  = threadIdx.x;
    const int blk  = blockIdx.x;
    const int bbase = blk * BT;
    const int l    = tid & 63;
    const int wv   = tid >> 6;          // wave 0..7
    const int cidx = l & 15;
    const int gidx = l >> 4;            // k-group 0..3
    const int jh   = 16 * wv + cidx;    // owned hidden column

    // A-panel: k = 0..127 decayed h (bf16), 128..148 x_c, 149..169 m, 170..191 zero.
    // Row stride 200 shorts (400 B, 16B-aligned rows, bank-spread).
    __shared__ unsigned short ak_s[BT][200];
    __shared__ unsigned short d_s[BT][40];     // bf16 deltas, cols 21..31 zero-pad
    __shared__ float x_s[BT][22], m_s[BT][22], xh_s[BT][22];
    __shared__ float hfin_s[BT][HID + 4];
    __shared__ float scrn_s[8], scrd_s[8];

    for (int i = tid; i < BT * 200; i += NTHR) ((unsigned short*)ak_s)[i] = 0;
    for (int i = tid; i < BT * 40;  i += NTHR) ((unsigned short*)d_s)[i] = 0;
    __syncthreads();   // zeros visible before per-owner writes below

    // ---------- one-time: B-fragments into registers (bf16) ----------
    // gates: combined K = [h(128) | x_c(21) m(21) | pad->192], cols = gate g of jh
    s16x8 bfr_g[4][6];
    #pragma unroll
    for (int g = 0; g < 4; ++g) {
        const float* rhh = W_hh + (g * HID + jh) * HID;
        const float* rih = W_ih + (g * HID + jh) * (2 * FEAT);
        #pragma unroll
        for (int s = 0; s < 6; ++s) {
            s16x8 fr;
            #pragma unroll
            for (int j = 0; j < 8; ++j) {
                int k = 32 * s + 8 * gidx + j;
                float w = (k < HID) ? rhh[k]
                        : ((k - HID) < 2 * FEAT ? rih[k - HID] : 0.0f);
                fr[j] = (short)to_bf16(w);
            }
            bfr_g[g][s] = fr;
        }
    }
    // gamma: B[col=jh][k=f<21]
    s16x8 bfr_d;
    {
        const float* rw = W_decay + jh * FEAT;
        #pragma unroll
        for (int j = 0; j < 8; ++j) {
            int f = 8 * gidx + j;
            bfr_d[j] = (short)to_bf16(f < FEAT ? rw[f] : 0.0f);
        }
    }
    // x_h regression: waves 0,1 own output cols f = 16*wv + cidx
    s16x8 bfr_r[4];
    float br_r = 0.0f;
    {
        int f = 16 * wv + cidx;
        bool fv = (wv < 2) && (f < FEAT);
        #pragma unroll
        for (int s = 0; s < 4; ++s) {
            s16x8 fr;
            #pragma unroll
            for (int j = 0; j < 8; ++j) {
                int k = 32 * s + 8 * gidx + j;
                fr[j] = (short)to_bf16(fv ? W_reg[f * HID + k] : 0.0f);
            }
            bfr_r[s] = fr;
        }
        if (fv) br_r = b_reg[f];
    }
    const float bd_r = b_decay[jh];
    float bs_r[4];
    #pragma unroll
    for (int g = 0; g < 4; ++g) bs_r[g] = b_ih[g * HID + jh] + b_hh[g * HID + jh];

    // ---------- preload t=0 inputs ----------
    const int rr = tid / FEAT, ff = tid - rr * FEAT;     // valid for tid < 336
    const int base_off = (bbase + rr) * (T_LEN * FEAT) + ff;
    if (tid < BT * FEAT) {
        x_s[rr][ff] = values[base_off];
        m_s[rr][ff] = masks[base_off];
        d_s[rr][ff] = to_bf16(deltas[base_off]);
    }

    float c_r[4] = {0.f, 0.f, 0.f, 0.f};
    float h_r[4] = {0.f, 0.f, 0.f, 0.f};
    __syncthreads();

    for (int t = 0; t < T_LEN; ++t) {
        // prefetch t+1 into regs (flushed to LDS in phase D)
        float px = 0.f, pm = 0.f, pd = 0.f;
        if (tid < BT * FEAT) {
            int o = base_off + ((t < T_LEN - 1) ? (t + 1) : t) * FEAT;
            px = values[o]; pm = masks[o]; pd = deltas[o];
        }

        // ---- A: gamma = exp(-relu(d@Wd^T+bd)); decay h (in-reg); h->bf16 panel ----
        {
            f32x4 gacc = {bd_r, bd_r, bd_r, bd_r};
            s16x8 ad = *(const s16x8*)&d_s[cidx][8 * gidx];
            gacc = MFMA16(ad, bfr_d, gacc);
            #pragma unroll
            for (int v = 0; v < 4; ++v) {
                float gam = __expf(-fmaxf(gacc[v], 0.0f));
                float hd = h_r[v] * gam;
                ak_s[4 * gidx + v][jh] = to_bf16(hd);
            }
        }
        __syncthreads();                       // (1) h-panel ready

        // ---- B: x_h = h @ W_reg^T + b_reg  (waves 0,1) ----
        if (wv < 2) {
            f32x4 xacc = {br_r, br_r, br_r, br_r};
            #pragma unroll
            for (int s = 0; s < 4; ++s) {
                s16x8 ah = *(const s16x8*)&ak_s[cidx][32 * s + 8 * gidx];
                xacc = MFMA16(ah, bfr_r[s], xacc);
            }
            int f = 16 * wv + cidx;
            if (f < FEAT) {
                #pragma unroll
                for (int v = 0; v < 4; ++v) xh_s[4 * gidx + v][f] = xacc[v];
            }
        }
        __syncthreads();                       // (2) xh ready

        // ---- B2: x_c, imputation write, loss partials, panel x_c/m ----
        float nd_num = 0.0f, nd_den = 0.0f;
        if (tid < BT * FEAT) {
            float xh = xh_s[rr][ff];
            float xv = x_s[rr][ff], mv = m_s[rr][ff];
            float xc = mv * xv + (1.0f - mv) * xh;
            out_imp[(bbase + rr) * (T_LEN * FEAT) + t * FEAT + ff] = xc;
            ak_s[rr][HID + ff]        = to_bf16(xc);
            ak_s[rr][HID + FEAT + ff] = to_bf16(mv);
            nd_num = fabsf(xv - xh) * mv;
            nd_den = mv;
        }
        #pragma unroll
        for (int s = 32; s > 0; s >>= 1) {
            nd_num += __shfl_down(nd_num, s);
            nd_den += __shfl_down(nd_den, s);
        }
        if (l == 0) { scrn_s[wv] = nd_num; scrd_s[wv] = nd_den; }
        __syncthreads();                       // (3) panel + scratch ready
        if (tid == 0) {
            float n = 0.f, d = 0.f;
            #pragma unroll
            for (int w = 0; w < 8; ++w) { n += scrn_s[w]; d += scrd_s[w]; }
            wsnum[t * NB + blk] = n;
            wsden[t * NB + blk] = d;
        }

        // ---- C: gates = [h|x_c|m] @ W^T + b   (24 MFMAs/wave) ----
        f32x4 acc0 = {bs_r[0], bs_r[0], bs_r[0], bs_r[0]};
        f32x4 acc1 = {bs_r[1], bs_r[1], bs_r[1], bs_r[1]};
        f32x4 acc2 = {bs_r[2], bs_r[2], bs_r[2], bs_r[2]};
        f32x4 acc3 = {bs_r[3], bs_r[3], bs_r[3], bs_r[3]};
        #pragma unroll
        for (int s = 0; s < 6; ++s) {
            s16x8 a = *(const s16x8*)&ak_s[cidx][32 * s + 8 * gidx];
            acc0 = MFMA16(a, bfr_g[0][s], acc0);
            acc1 = MFMA16(a, bfr_g[1][s], acc1);
            acc2 = MFMA16(a, bfr_g[2][s], acc2);
            acc3 = MFMA16(a, bfr_g[3][s], acc3);
        }

        // ---- D: LSTM pointwise (all in regs), flush prefetch ----
        #pragma unroll
        for (int v = 0; v < 4; ++v) {
            float ig = sigmoid_f(acc0[v]);
            float fg = sigmoid_f(acc1[v]);
            float gg = tanh_f(acc2[v]);
            float og = sigmoid_f(acc3[v]);
            c_r[v] = fg * c_r[v] + ig * gg;
            h_r[v] = og * tanh_f(c_r[v]);
        }
        if (tid < BT * FEAT) {
            x_s[rr][ff] = px;
            m_s[rr][ff] = pm;
            d_s[rr][ff] = to_bf16(pd);
        }
        __syncthreads();                       // (4) end of step
    }

    // ---------- epilogue: y_h, y_loss partials ----------
    #pragma unroll
    for (int v = 0; v < 4; ++v) hfin_s[4 * gidx + v][jh] = h_r[v];
    __syncthreads();

    float yerr = 0.0f, ytr = 0.0f;
    if (tid < BT) {
        float acc = b_out[0];
        for (int k = 0; k < HID; ++k) acc += W_out[k] * hfin_s[tid][k];
        out_yh[bbase + tid] = acc;
        float it = is_train[bbase + tid];
        float dv = acc - labels[bbase + tid];
        yerr = dv * dv * it;
        ytr  = it;
    }
    #pragma unroll
    for (int s = 8; s > 0; s >>= 1) {
        yerr += __shfl_down(yerr, s);
        ytr  += __shfl_down(ytr, s);
    }
    if (tid == 0) { wsynum[blk] = yerr; wsyden[blk] = ytr; }
}

__global__ __launch_bounds__(256) void rits_final(
    const float* __restrict__ wsnum, const float* __restrict__ wsden,
    const float* __restrict__ wsynum, const float* __restrict__ wsyden,
    float* __restrict__ d_out)
{
    __shared__ float sx[256], sy[256], sz[256];
    int tid = threadIdx.x;
    float v = 0.0f;
    if (tid < T_LEN) {
        float n = 0.f, d = 0.f;
        for (int b = 0; b < NB; ++b) { n += wsnum[tid * NB + b]; d += wsden[tid * NB + b]; }
        v = n / (d + 1e-5f);
    }
    sx[tid] = v;
    sy[tid] = wsynum[tid];
    sz[tid] = wsyden[tid];
    __syncthreads();
    for (int s = 128; s > 0; s >>= 1) {
        if (tid < s) { sx[tid] += sx[tid + s]; sy[tid] += sy[tid + s]; sz[tid] += sz[tid + s]; }
        __syncthreads();
    }
    if (tid == 0) d_out[0] = sx[0] + sy[0] / (sz[0] + 1e-5f);
}

extern "C" void kernel_launch(void* const* d_in, const int* in_sizes, int n_in,
                              void* d_out, int out_size, void* d_ws, size_t ws_size,
                              hipStream_t stream)
{
    const float* values    = (const float*)d_in[0];
    const float* masks     = (const float*)d_in[1];
    const float* deltas    = (const float*)d_in[2];
    // d_in[3] evals, d_in[4] eval_masks : unused
    const float* labels    = (const float*)d_in[5];
    const float* is_train  = (const float*)d_in[6];
    const float* W_decay   = (const float*)d_in[7];
    const float* b_decay   = (const float*)d_in[8];
    const float* W_reg     = (const float*)d_in[9];
    const float* b_reg     = (const float*)d_in[10];
    const float* W_ih      = (const float*)d_in[11];
    const float* W_hh      = (const float*)d_in[12];
    const float* b_ih      = (const float*)d_in[13];
    const float* b_hh      = (const float*)d_in[14];
    const float* W_out     = (const float*)d_in[15];
    const float* b_out     = (const float*)d_in[16];

    float* ws     = (float*)d_ws;
    float* wsnum  = ws + WS_NUM;
    float* wsden  = ws + WS_DEN;
    float* wsynum = ws + WS_YNUM;
    float* wsyden = ws + WS_YDEN;

    float* out     = (float*)d_out;
    float* out_yh  = out + 1;
    float* out_imp = out + 1 + BTOT;

    rits_main<<<dim3(NB), dim3(NTHR), 0, stream>>>(
        values, masks, deltas, labels, is_train,
        W_decay, b_decay, W_reg, b_reg, W_ih, W_hh, b_ih, b_hh, W_out, b_out,
        out_yh, out_imp, wsnum, wsden, wsynum, wsyden);

    rits_final<<<dim3(1), dim3(256), 0, stream>>>(wsnum, wsden, wsynum, wsyden, out);
}

// Round 3
// 637.926 us; speedup vs baseline: 5.6550x; 1.0002x over previous
//
#include <hip/hip_runtime.h>
#include <math.h>

// RITS recurrent model, MFMA bf16, pipelined 3-barrier step loop.
// 256 blocks x 512 threads (8 waves), block owns 16 batch rows.
// Wave w owns hidden cols jh in [16w,16w+16). MFMA 16x16x32 lane layout:
//   cidx = lane&15 (A row / D col), gidx = lane>>4 (k-group of 8)
//   D: row = 4*gidx+v, col = cidx  [m89-verified]
// Per-step schedule (3 barriers):
//   A : hd = h*gamma (gamma precomputed last step) -> panel[t&1]; issue loads t+2
//   bar1
//   B : waves 0,1: x_h MFMAs -> xh_s; all waves: gate MFMAs s=0..3 (h part)
//   bar2
//   B2: x_c, imputation store, loss partials, panel xc/m cols, flush prefetch
//   bar3
//   C : gamma(t+1) MFMA (d_s other parity) + gate MFMAs s=4,5 (xc|m part)
//   D : LSTM pointwise (regs) + gamma(t+1) exp    [no barrier: panel dbuf]

#define T_LEN 252
#define FEAT  21
#define HID   128
#define BTOT  4096
#define BT    16
#define NB    (BTOT / BT)   // 256
#define NTHR  512

#define WS_NUM    0
#define WS_DEN    (T_LEN * NB)
#define WS_YNUM   (2 * T_LEN * NB)
#define WS_YDEN   (2 * T_LEN * NB + NB)

typedef __attribute__((ext_vector_type(8))) short s16x8;
typedef __attribute__((ext_vector_type(4))) float f32x4;

#define MFMA16(A, B, C) __builtin_amdgcn_mfma_f32_16x16x32_bf16((A), (B), (C), 0, 0, 0)

__device__ __forceinline__ float sigmoid_f(float x) { return 1.0f / (1.0f + __expf(-x)); }
__device__ __forceinline__ float tanh_f(float x) {
    return 2.0f / (1.0f + __expf(-2.0f * x)) - 1.0f;
}
__device__ __forceinline__ unsigned short to_bf16(float x) {
    unsigned int u = __float_as_uint(x);
    unsigned int r = (u + 0x7FFFu + ((u >> 16) & 1u)) >> 16;   // RNE
    return (unsigned short)r;
}

__global__ __launch_bounds__(NTHR, 2) void rits_main(
    const float* __restrict__ values, const float* __restrict__ masks,
    const float* __restrict__ deltas,
    const float* __restrict__ labels, const float* __restrict__ is_train,
    const float* __restrict__ W_decay, const float* __restrict__ b_decay,
    const float* __restrict__ W_reg, const float* __restrict__ b_reg,
    const float* __restrict__ W_ih, const float* __restrict__ W_hh,
    const float* __restrict__ b_ih, const float* __restrict__ b_hh,
    const float* __restrict__ W_out, const float* __restrict__ b_out,
    float* __restrict__ out_yh,     // [BTOT]
    float* __restrict__ out_imp,    // [BTOT][T][FEAT]
    float* __restrict__ wsnum, float* __restrict__ wsden,
    float* __restrict__ wsynum, float* __restrict__ wsyden)
{
    const int tid  = threadIdx.x;
    const int blk  = blockIdx.x;
    const int bbase = blk * BT;
    const int l    = tid & 63;
    const int wv   = tid >> 6;          // wave 0..7
    const int cidx = l & 15;
    const int gidx = l >> 4;            // k-group 0..3
    const int jh   = 16 * wv + cidx;    // owned hidden column

    // Double-buffered A-panel: k = 0..127 decayed h, 128..148 x_c, 149..169 m,
    // 170..191 zero. Row stride 200 shorts (400 B).
    __shared__ unsigned short ak_s[2][BT][200];
    __shared__ unsigned short d_s[2][BT][40];   // bf16 deltas, cols 21..39 zero
    __shared__ float x_s[2][BT][22], m_s[2][BT][22];
    __shared__ float xh_s[BT][22];
    __shared__ float hfin_s[BT][HID + 4];
    __shared__ float scrn_s[8], scrd_s[8];

    for (int i = tid; i < 2 * BT * 200; i += NTHR) ((unsigned short*)ak_s)[i] = 0;
    for (int i = tid; i < 2 * BT * 40;  i += NTHR) ((unsigned short*)d_s)[i] = 0;
    __syncthreads();   // zeros visible before per-owner writes

    // ---------- one-time: B-fragments into registers (bf16) ----------
    s16x8 bfr_g[4][6];
    #pragma unroll
    for (int g = 0; g < 4; ++g) {
        const float* rhh = W_hh + (g * HID + jh) * HID;
        const float* rih = W_ih + (g * HID + jh) * (2 * FEAT);
        #pragma unroll
        for (int s = 0; s < 6; ++s) {
            s16x8 fr;
            #pragma unroll
            for (int j = 0; j < 8; ++j) {
                int k = 32 * s + 8 * gidx + j;
                float w = (k < HID) ? rhh[k]
                        : ((k - HID) < 2 * FEAT ? rih[k - HID] : 0.0f);
                fr[j] = (short)to_bf16(w);
            }
            bfr_g[g][s] = fr;
        }
    }
    s16x8 bfr_d;
    {
        const float* rw = W_decay + jh * FEAT;
        #pragma unroll
        for (int j = 0; j < 8; ++j) {
            int f = 8 * gidx + j;
            bfr_d[j] = (short)to_bf16(f < FEAT ? rw[f] : 0.0f);
        }
    }
    s16x8 bfr_r[4];
    float br_r = 0.0f;
    {
        int f = 16 * wv + cidx;
        bool fv = (wv < 2) && (f < FEAT);
        #pragma unroll
        for (int s = 0; s < 4; ++s) {
            s16x8 fr;
            #pragma unroll
            for (int j = 0; j < 8; ++j) {
                int k = 32 * s + 8 * gidx + j;
                fr[j] = (short)to_bf16(fv ? W_reg[f * HID + k] : 0.0f);
            }
            bfr_r[s] = fr;
        }
        if (fv) br_r = b_reg[f];
    }
    const float bd_r = b_decay[jh];
    float bs_r[4];
    #pragma unroll
    for (int g = 0; g < 4; ++g) bs_r[g] = b_ih[g * HID + jh] + b_hh[g * HID + jh];

    // ---------- prologue: t=0 -> LDS, t=1 -> prefetch regs ----------
    const int rr = tid / FEAT, ff = tid - rr * FEAT;    // valid for tid < 336
    const int rowbase = (bbase + rr) * (T_LEN * FEAT) + ff;
    float pAx = 0.f, pAm = 0.f, pAd = 0.f;
    if (tid < BT * FEAT) {
        x_s[0][rr][ff] = values[rowbase];
        m_s[0][rr][ff] = masks[rowbase];
        pAx = values[rowbase + FEAT];
        pAm = masks[rowbase + FEAT];
        pAd = deltas[rowbase + FEAT];
    }
    float c_r[4]  = {0.f, 0.f, 0.f, 0.f};
    float h_r[4]  = {0.f, 0.f, 0.f, 0.f};
    float gam_r[4] = {0.f, 0.f, 0.f, 0.f};   // h=0 at t=0 -> value irrelevant
    __syncthreads();

    for (int t = 0; t < T_LEN; ++t) {
        const int par = t & 1;

        // ---- A: write decayed h to panel[par]; issue t+2 loads ----
        float pBx = 0.f, pBm = 0.f, pBd = 0.f;
        if (tid < BT * FEAT) {
            int idx = (t + 2 < T_LEN) ? (t + 2) : (T_LEN - 1);
            int o = rowbase + idx * FEAT;
            pBx = values[o]; pBm = masks[o]; pBd = deltas[o];
        }
        #pragma unroll
        for (int v = 0; v < 4; ++v)
            ak_s[par][4 * gidx + v][jh] = to_bf16(h_r[v] * gam_r[v]);
        __syncthreads();                                // bar1

        // ---- B: x_h (waves 0,1) + gates s=0..3 (all waves) ----
        s16x8 aF0 = *(const s16x8*)&ak_s[par][cidx][      8 * gidx];
        s16x8 aF1 = *(const s16x8*)&ak_s[par][cidx][ 32 + 8 * gidx];
        s16x8 aF2 = *(const s16x8*)&ak_s[par][cidx][ 64 + 8 * gidx];
        s16x8 aF3 = *(const s16x8*)&ak_s[par][cidx][ 96 + 8 * gidx];
        if (wv < 2) {
            f32x4 xacc = {br_r, br_r, br_r, br_r};
            xacc = MFMA16(aF0, bfr_r[0], xacc);
            xacc = MFMA16(aF1, bfr_r[1], xacc);
            xacc = MFMA16(aF2, bfr_r[2], xacc);
            xacc = MFMA16(aF3, bfr_r[3], xacc);
            int f = 16 * wv + cidx;
            if (f < FEAT) {
                #pragma unroll
                for (int v = 0; v < 4; ++v) xh_s[4 * gidx + v][f] = xacc[v];
            }
        }
        f32x4 acc0 = {bs_r[0], bs_r[0], bs_r[0], bs_r[0]};
        f32x4 acc1 = {bs_r[1], bs_r[1], bs_r[1], bs_r[1]};
        f32x4 acc2 = {bs_r[2], bs_r[2], bs_r[2], bs_r[2]};
        f32x4 acc3 = {bs_r[3], bs_r[3], bs_r[3], bs_r[3]};
        acc0 = MFMA16(aF0, bfr_g[0][0], acc0); acc1 = MFMA16(aF0, bfr_g[1][0], acc1);
        acc2 = MFMA16(aF0, bfr_g[2][0], acc2); acc3 = MFMA16(aF0, bfr_g[3][0], acc3);
        acc0 = MFMA16(aF1, bfr_g[0][1], acc0); acc1 = MFMA16(aF1, bfr_g[1][1], acc1);
        acc2 = MFMA16(aF1, bfr_g[2][1], acc2); acc3 = MFMA16(aF1, bfr_g[3][1], acc3);
        acc0 = MFMA16(aF2, bfr_g[0][2], acc0); acc1 = MFMA16(aF2, bfr_g[1][2], acc1);
        acc2 = MFMA16(aF2, bfr_g[2][2], acc2); acc3 = MFMA16(aF2, bfr_g[3][2], acc3);
        acc0 = MFMA16(aF3, bfr_g[0][3], acc0); acc1 = MFMA16(aF3, bfr_g[1][3], acc1);
        acc2 = MFMA16(aF3, bfr_g[2][3], acc2); acc3 = MFMA16(aF3, bfr_g[3][3], acc3);
        __syncthreads();                                // bar2

        // ---- B2: x_c, imputation, loss, panel xc/m, prefetch flush ----
        float nd_num = 0.0f, nd_den = 0.0f;
        if (tid < BT * FEAT) {
            float xh = xh_s[rr][ff];
            float xv = x_s[par][rr][ff], mv = m_s[par][rr][ff];
            float xc = mv * xv + (1.0f - mv) * xh;
            out_imp[rowbase + t * FEAT] = xc;
            ak_s[par][rr][HID + ff]        = to_bf16(xc);
            ak_s[par][rr][HID + FEAT + ff] = to_bf16(mv);
            nd_num = fabsf(xv - xh) * mv;
            nd_den = mv;
            int q = par ^ 1;                 // flush t+1 data
            x_s[q][rr][ff] = pAx;
            m_s[q][rr][ff] = pAm;
            d_s[q][rr][ff] = to_bf16(pAd);
            pAx = pBx; pAm = pBm; pAd = pBd;
        }
        #pragma unroll
        for (int s = 32; s > 0; s >>= 1) {
            nd_num += __shfl_down(nd_num, s);
            nd_den += __shfl_down(nd_den, s);
        }
        if (l == 0) { scrn_s[wv] = nd_num; scrd_s[wv] = nd_den; }
        __syncthreads();                                // bar3
        if (tid == 0) {
            float n = 0.f, d = 0.f;
            #pragma unroll
            for (int w = 0; w < 8; ++w) { n += scrn_s[w]; d += scrd_s[w]; }
            wsnum[t * NB + blk] = n;
            wsden[t * NB + blk] = d;
        }

        // ---- C: gamma(t+1) MFMA + gates s=4,5 ----
        s16x8 ad = *(const s16x8*)&d_s[par ^ 1][cidx][8 * gidx];
        f32x4 gacc = {bd_r, bd_r, bd_r, bd_r};
        gacc = MFMA16(ad, bfr_d, gacc);
        s16x8 a4 = *(const s16x8*)&ak_s[par][cidx][128 + 8 * gidx];
        s16x8 a5 = *(const s16x8*)&ak_s[par][cidx][160 + 8 * gidx];
        acc0 = MFMA16(a4, bfr_g[0][4], acc0); acc0 = MFMA16(a5, bfr_g[0][5], acc0);
        acc1 = MFMA16(a4, bfr_g[1][4], acc1); acc1 = MFMA16(a5, bfr_g[1][5], acc1);
        acc2 = MFMA16(a4, bfr_g[2][4], acc2); acc2 = MFMA16(a5, bfr_g[2][5], acc2);
        acc3 = MFMA16(a4, bfr_g[3][4], acc3); acc3 = MFMA16(a5, bfr_g[3][5], acc3);

        // ---- D: LSTM pointwise + gamma(t+1) exp (all in regs) ----
        #pragma unroll
        for (int v = 0; v < 4; ++v) {
            float ig = sigmoid_f(acc0[v]);
            float fg = sigmoid_f(acc1[v]);
            float gg = tanh_f(acc2[v]);
            float og = sigmoid_f(acc3[v]);
            c_r[v] = fg * c_r[v] + ig * gg;
            h_r[v] = og * tanh_f(c_r[v]);
            gam_r[v] = __expf(-fmaxf(gacc[v], 0.0f));
        }
        // no barrier: next A writes panel[par^1], disjoint from this step's reads
    }

    // ---------- epilogue: y_h, y_loss partials ----------
    #pragma unroll
    for (int v = 0; v < 4; ++v) hfin_s[4 * gidx + v][jh] = h_r[v];
    __syncthreads();

    float yerr = 0.0f, ytr = 0.0f;
    if (tid < BT) {
        float acc = b_out[0];
        for (int k = 0; k < HID; ++k) acc += W_out[k] * hfin_s[tid][k];
        out_yh[bbase + tid] = acc;
        float it = is_train[bbase + tid];
        float dv = acc - labels[bbase + tid];
        yerr = dv * dv * it;
        ytr  = it;
    }
    #pragma unroll
    for (int s = 8; s > 0; s >>= 1) {
        yerr += __shfl_down(yerr, s);
        ytr  += __shfl_down(ytr, s);
    }
    if (tid == 0) { wsynum[blk] = yerr; wsyden[blk] = ytr; }
}

__global__ __launch_bounds__(256) void rits_final(
    const float* __restrict__ wsnum, const float* __restrict__ wsden,
    const float* __restrict__ wsynum, const float* __restrict__ wsyden,
    float* __restrict__ d_out)
{
    __shared__ float sx[256], sy[256], sz[256];
    int tid = threadIdx.x;
    float v = 0.0f;
    if (tid < T_LEN) {
        float n = 0.f, d = 0.f;
        for (int b = 0; b < NB; ++b) { n += wsnum[tid * NB + b]; d += wsden[tid * NB + b]; }
        v = n / (d + 1e-5f);
    }
    sx[tid] = v;
    sy[tid] = wsynum[tid];
    sz[tid] = wsyden[tid];
    __syncthreads();
    for (int s = 128; s > 0; s >>= 1) {
        if (tid < s) { sx[tid] += sx[tid + s]; sy[tid] += sy[tid + s]; sz[tid] += sz[tid + s]; }
        __syncthreads();
    }
    if (tid == 0) d_out[0] = sx[0] + sy[0] / (sz[0] + 1e-5f);
}

extern "C" void kernel_launch(void* const* d_in, const int* in_sizes, int n_in,
                              void* d_out, int out_size, void* d_ws, size_t ws_size,
                              hipStream_t stream)
{
    const float* values    = (const float*)d_in[0];
    const float* masks     = (const float*)d_in[1];
    const float* deltas    = (const float*)d_in[2];
    // d_in[3] evals, d_in[4] eval_masks : unused
    const float* labels    = (const float*)d_in[5];
    const float* is_train  = (const float*)d_in[6];
    const float* W_decay   = (const float*)d_in[7];
    const float* b_decay   = (const float*)d_in[8];
    const float* W_reg     = (const float*)d_in[9];
    const float* b_reg     = (const float*)d_in[10];
    const float* W_ih      = (const float*)d_in[11];
    const float* W_hh      = (const float*)d_in[12];
    const float* b_ih      = (const float*)d_in[13];
    const float* b_hh      = (const float*)d_in[14];
    const float* W_out     = (const float*)d_in[15];
    const float* b_out     = (const float*)d_in[16];

    float* ws     = (float*)d_ws;
    float* wsnum  = ws + WS_NUM;
    float* wsden  = ws + WS_DEN;
    float* wsynum = ws + WS_YNUM;
    float* wsyden = ws + WS_YDEN;

    float* out     = (float*)d_out;
    float* out_yh  = out + 1;
    float* out_imp = out + 1 + BTOT;

    rits_main<<<dim3(NB), dim3(NTHR), 0, stream>>>(
        values, masks, deltas, labels, is_train,
        W_decay, b_decay, W_reg, b_reg, W_ih, W_hh, b_ih, b_hh, W_out, b_out,
        out_yh, out_imp, wsnum, wsden, wsynum, wsyden);

    rits_final<<<dim3(1), dim3(256), 0, stream>>>(wsnum, wsden, wsynum, wsyden, out);
}

// Round 4
// 578.230 us; speedup vs baseline: 6.2388x; 1.1032x over previous
//
#include <hip/hip_runtime.h>
#include <math.h>

// RITS recurrent model, MFMA bf16, register-resident loss accumulation.
// 256 blocks x 512 threads (8 waves), block owns 16 batch rows.
// Wave w owns hidden cols jh in [16w,16w+16). MFMA 16x16x32 lane layout:
//   cidx = lane&15 (A row / D col), gidx = lane>>4 (k-group of 8)
//   D: row = 4*gidx+v, col = cidx  [m89-verified]
// Per-step (3 barriers):
//   A : flush d(t+1)->d_s[par^1]; issue loads t+2; h*gamma -> panel[par]
//   bar1
//   B : waves 0,1: x_h MFMAs -> xh_s; all waves: gate MFMAs s=0..3 (h part)
//   bar2
//   B2: x_c (regs), imputation store, xl_acc += |x-xh|*m*rden[t],
//       packed xc|m -> panel cols 128.., register shift
//   bar3
//   C : gamma(t+1) MFMA (d_s[par^1]) + gate MFMAs s=4,5 (xc|m interleaved)
//   D : LSTM pointwise + gamma exp (all regs; no barrier: panel dbuf)
// Loss: den_t precomputed by rits_den (input-only), per-thread accumulate,
// one epilogue tree reduce -> ws, final kernel sums 256 partials.

#define T_LEN 252
#define FEAT  21
#define HID   128
#define BTOT  4096
#define BT    16
#define NB    (BTOT / BT)   // 256
#define NTHR  512

// ws layout (floats)
#define WS_RDEN   0      // [256] (252 used)
#define WS_XL     256    // [256]
#define WS_YNUM   512    // [256]
#define WS_YDEN   768    // [256]

typedef __attribute__((ext_vector_type(8))) short s16x8;
typedef __attribute__((ext_vector_type(4))) float f32x4;

#define MFMA16(A, B, C) __builtin_amdgcn_mfma_f32_16x16x32_bf16((A), (B), (C), 0, 0, 0)

__device__ __forceinline__ float sigmoid_f(float x) { return 1.0f / (1.0f + __expf(-x)); }
__device__ __forceinline__ float tanh_f(float x) {
    return 2.0f / (1.0f + __expf(-2.0f * x)) - 1.0f;
}
__device__ __forceinline__ unsigned short to_bf16(float x) {   // RNE (setup only)
    unsigned int u = __float_as_uint(x);
    return (unsigned short)((u + 0x7FFFu + ((u >> 16) & 1u)) >> 16);
}
__device__ __forceinline__ unsigned short to_bf16f(float x) {  // round-half-up, 2 ops
    return (unsigned short)((__float_as_uint(x) + 0x8000u) >> 16);
}

// ---- pre-pass: rden[t] = 1 / (sum_{b,f} masks[b][t][f] + 1e-5) ----
__global__ __launch_bounds__(1024) void rits_den(
    const float* __restrict__ masks, float* __restrict__ rden)
{
    const int t = blockIdx.x;
    const int tid = threadIdx.x;
    __shared__ float red[1024];
    float acc = 0.0f;
    if (tid < 48 * FEAT) {                     // 1008 active
        int r0 = tid / FEAT, f = tid - r0 * FEAT;
        for (int r = r0; r < BTOT; r += 48)
            acc += masks[r * (T_LEN * FEAT) + t * FEAT + f];
    }
    red[tid] = acc;
    __syncthreads();
    #pragma unroll
    for (int s = 512; s > 0; s >>= 1) {
        if (tid < s) red[tid] += red[tid + s];
        __syncthreads();
    }
    if (tid == 0) rden[t] = 1.0f / (red[0] + 1e-5f);
}

__global__ __launch_bounds__(NTHR, 2) void rits_main(
    const float* __restrict__ values, const float* __restrict__ masks,
    const float* __restrict__ deltas,
    const float* __restrict__ labels, const float* __restrict__ is_train,
    const float* __restrict__ W_decay, const float* __restrict__ b_decay,
    const float* __restrict__ W_reg, const float* __restrict__ b_reg,
    const float* __restrict__ W_ih, const float* __restrict__ W_hh,
    const float* __restrict__ b_ih, const float* __restrict__ b_hh,
    const float* __restrict__ W_out, const float* __restrict__ b_out,
    const float* __restrict__ rden,
    float* __restrict__ out_yh,     // [BTOT]
    float* __restrict__ out_imp,    // [BTOT][T][FEAT]
    float* __restrict__ xlpart, float* __restrict__ wsynum, float* __restrict__ wsyden)
{
    const int tid  = threadIdx.x;
    const int blk  = blockIdx.x;
    const int bbase = blk * BT;
    const int l    = tid & 63;
    const int wv   = tid >> 6;          // wave 0..7
    const int cidx = l & 15;
    const int gidx = l >> 4;            // k-group 0..3
    const int jh   = 16 * wv + cidx;    // owned hidden column

    // Double-buffered A-panel: k 0..127 decayed h; 128+2f = x_c[f], 128+2f+1 = m[f]
    // (f<21 -> k 128..169); 170..199 zero. Row stride 200 shorts.
    __shared__ unsigned short ak_s[2][BT][200];
    __shared__ unsigned short d_s[2][BT][40];   // bf16 deltas, cols 21..39 zero
    __shared__ float xh_s[BT][22];
    __shared__ float hfin_s[BT][HID + 4];
    __shared__ float rden_s[T_LEN];
    __shared__ float red_s[NTHR];

    for (int i = tid; i < 2 * BT * 200; i += NTHR) ((unsigned short*)ak_s)[i] = 0;
    for (int i = tid; i < 2 * BT * 40;  i += NTHR) ((unsigned short*)d_s)[i] = 0;
    if (tid < T_LEN) rden_s[tid] = rden[tid];

    // ---------- one-time: B-fragments into registers (bf16) ----------
    // gates: K = [h(128) | interleaved xc,m (42) | pad->192], col = gate g of jh
    s16x8 bfr_g[4][6];
    #pragma unroll
    for (int g = 0; g < 4; ++g) {
        const float* rhh = W_hh + (g * HID + jh) * HID;
        const float* rih = W_ih + (g * HID + jh) * (2 * FEAT);
        #pragma unroll
        for (int s = 0; s < 6; ++s) {
            s16x8 fr;
            #pragma unroll
            for (int j = 0; j < 8; ++j) {
                int k = 32 * s + 8 * gidx + j;
                float w;
                if (k < HID) w = rhh[k];
                else {
                    int kk = k - HID, f2 = kk >> 1, sel = kk & 1;
                    w = (f2 < FEAT) ? (sel ? rih[FEAT + f2] : rih[f2]) : 0.0f;
                }
                fr[j] = (short)to_bf16(w);
            }
            bfr_g[g][s] = fr;
        }
    }
    s16x8 bfr_d;
    {
        const float* rw = W_decay + jh * FEAT;
        #pragma unroll
        for (int j = 0; j < 8; ++j) {
            int f = 8 * gidx + j;
            bfr_d[j] = (short)to_bf16(f < FEAT ? rw[f] : 0.0f);
        }
    }
    s16x8 bfr_r[4];
    float br_r = 0.0f;
    {
        int f = 16 * wv + cidx;
        bool fv = (wv < 2) && (f < FEAT);
        #pragma unroll
        for (int s = 0; s < 4; ++s) {
            s16x8 fr;
            #pragma unroll
            for (int j = 0; j < 8; ++j) {
                int k = 32 * s + 8 * gidx + j;
                fr[j] = (short)to_bf16(fv ? W_reg[f * HID + k] : 0.0f);
            }
            bfr_r[s] = fr;
        }
        if (fv) br_r = b_reg[f];
    }
    const float bd_r = b_decay[jh];
    float bs_r[4];
    #pragma unroll
    for (int g = 0; g < 4; ++g) bs_r[g] = b_ih[g * HID + jh] + b_hh[g * HID + jh];

    // ---------- prologue: t=0 and t=1 into registers ----------
    const int rr = tid / FEAT, ff = tid - rr * FEAT;    // valid for tid < 336
    const int rowbase = (bbase + rr) * (T_LEN * FEAT) + ff;
    float cx = 0.f, cm = 0.f;          // x,m at t
    float nx = 0.f, nm = 0.f, nd = 0.f; // x,m,d at t+1
    if (tid < BT * FEAT) {
        cx = values[rowbase];
        cm = masks[rowbase];
        nx = values[rowbase + FEAT];
        nm = masks[rowbase + FEAT];
        nd = deltas[rowbase + FEAT];
    }
    float c_r[4]  = {0.f, 0.f, 0.f, 0.f};
    float h_r[4]  = {0.f, 0.f, 0.f, 0.f};
    float gam_r[4] = {0.f, 0.f, 0.f, 0.f};   // h=0 at t=0 -> value irrelevant
    float xl_acc = 0.0f;
    __syncthreads();

    for (int t = 0; t < T_LEN; ++t) {
        const int par = t & 1;

        // ---- A: flush d(t+1); issue t+2 loads; decayed h -> panel[par] ----
        float lx = 0.f, lm = 0.f, ld = 0.f;
        float rd = rden_s[t];
        if (tid < BT * FEAT) {
            d_s[par ^ 1][rr][ff] = to_bf16f(nd);
            int idx = (t + 2 < T_LEN) ? (t + 2) : (T_LEN - 1);
            int o = rowbase + idx * FEAT;
            lx = values[o]; lm = masks[o]; ld = deltas[o];
        }
        #pragma unroll
        for (int v = 0; v < 4; ++v)
            ak_s[par][4 * gidx + v][jh] = to_bf16f(h_r[v] * gam_r[v]);
        __syncthreads();                                // bar1

        // ---- B: x_h (waves 0,1) + gates s=0..3 (all waves) ----
        s16x8 aF0 = *(const s16x8*)&ak_s[par][cidx][      8 * gidx];
        s16x8 aF1 = *(const s16x8*)&ak_s[par][cidx][ 32 + 8 * gidx];
        s16x8 aF2 = *(const s16x8*)&ak_s[par][cidx][ 64 + 8 * gidx];
        s16x8 aF3 = *(const s16x8*)&ak_s[par][cidx][ 96 + 8 * gidx];
        if (wv < 2) {
            f32x4 xacc = {br_r, br_r, br_r, br_r};
            xacc = MFMA16(aF0, bfr_r[0], xacc);
            xacc = MFMA16(aF1, bfr_r[1], xacc);
            xacc = MFMA16(aF2, bfr_r[2], xacc);
            xacc = MFMA16(aF3, bfr_r[3], xacc);
            int f = 16 * wv + cidx;
            if (f < FEAT) {
                #pragma unroll
                for (int v = 0; v < 4; ++v) xh_s[4 * gidx + v][f] = xacc[v];
            }
        }
        f32x4 acc0 = {bs_r[0], bs_r[0], bs_r[0], bs_r[0]};
        f32x4 acc1 = {bs_r[1], bs_r[1], bs_r[1], bs_r[1]};
        f32x4 acc2 = {bs_r[2], bs_r[2], bs_r[2], bs_r[2]};
        f32x4 acc3 = {bs_r[3], bs_r[3], bs_r[3], bs_r[3]};
        acc0 = MFMA16(aF0, bfr_g[0][0], acc0); acc1 = MFMA16(aF0, bfr_g[1][0], acc1);
        acc2 = MFMA16(aF0, bfr_g[2][0], acc2); acc3 = MFMA16(aF0, bfr_g[3][0], acc3);
        acc0 = MFMA16(aF1, bfr_g[0][1], acc0); acc1 = MFMA16(aF1, bfr_g[1][1], acc1);
        acc2 = MFMA16(aF1, bfr_g[2][1], acc2); acc3 = MFMA16(aF1, bfr_g[3][1], acc3);
        acc0 = MFMA16(aF2, bfr_g[0][2], acc0); acc1 = MFMA16(aF2, bfr_g[1][2], acc1);
        acc2 = MFMA16(aF2, bfr_g[2][2], acc2); acc3 = MFMA16(aF2, bfr_g[3][2], acc3);
        acc0 = MFMA16(aF3, bfr_g[0][3], acc0); acc1 = MFMA16(aF3, bfr_g[1][3], acc1);
        acc2 = MFMA16(aF3, bfr_g[2][3], acc2); acc3 = MFMA16(aF3, bfr_g[3][3], acc3);
        __syncthreads();                                // bar2

        // ---- B2: x_c, imputation, loss accumulate, packed panel write ----
        if (tid < BT * FEAT) {
            float xh = xh_s[rr][ff];
            float xc = cm * cx + (1.0f - cm) * xh;
            out_imp[rowbase + t * FEAT] = xc;
            unsigned int pk = ((unsigned int)to_bf16f(cm) << 16) | (unsigned int)to_bf16f(xc);
            *(unsigned int*)&ak_s[par][rr][HID + 2 * ff] = pk;
            xl_acc += fabsf(cx - xh) * cm * rd;
            cx = nx; cm = nm;
            nx = lx; nm = lm; nd = ld;
        }
        __syncthreads();                                // bar3

        // ---- C: gamma(t+1) MFMA + gates s=4,5 ----
        s16x8 ad = *(const s16x8*)&d_s[par ^ 1][cidx][8 * gidx];
        f32x4 gacc = {bd_r, bd_r, bd_r, bd_r};
        gacc = MFMA16(ad, bfr_d, gacc);
        s16x8 a4 = *(const s16x8*)&ak_s[par][cidx][128 + 8 * gidx];
        s16x8 a5 = *(const s16x8*)&ak_s[par][cidx][160 + 8 * gidx];
        acc0 = MFMA16(a4, bfr_g[0][4], acc0); acc0 = MFMA16(a5, bfr_g[0][5], acc0);
        acc1 = MFMA16(a4, bfr_g[1][4], acc1); acc1 = MFMA16(a5, bfr_g[1][5], acc1);
        acc2 = MFMA16(a4, bfr_g[2][4], acc2); acc2 = MFMA16(a5, bfr_g[2][5], acc2);
        acc3 = MFMA16(a4, bfr_g[3][4], acc3); acc3 = MFMA16(a5, bfr_g[3][5], acc3);

        // ---- D: LSTM pointwise + gamma(t+1) exp (all regs) ----
        #pragma unroll
        for (int v = 0; v < 4; ++v) {
            float ig = sigmoid_f(acc0[v]);
            float fg = sigmoid_f(acc1[v]);
            float gg = tanh_f(acc2[v]);
            float og = sigmoid_f(acc3[v]);
            c_r[v] = fg * c_r[v] + ig * gg;
            h_r[v] = og * tanh_f(c_r[v]);
            gam_r[v] = __expf(-fmaxf(gacc[v], 0.0f));
        }
        // no barrier: next A writes panel[par^1] h-cols / d_s[par], both
        // barrier-separated from this step's readers.
    }

    // ---------- epilogue ----------
    #pragma unroll
    for (int v = 0; v < 4; ++v) hfin_s[4 * gidx + v][jh] = h_r[v];
    red_s[tid] = xl_acc;
    __syncthreads();
    #pragma unroll
    for (int s = NTHR / 2; s > 0; s >>= 1) {
        if (tid < s) red_s[tid] += red_s[tid + s];
        __syncthreads();
    }
    if (tid == 0) xlpart[blk] = red_s[0];

    float yerr = 0.0f, ytr = 0.0f;
    if (tid < BT) {
        float acc = b_out[0];
        for (int k = 0; k < HID; ++k) acc += W_out[k] * hfin_s[tid][k];
        out_yh[bbase + tid] = acc;
        float it = is_train[bbase + tid];
        float dv = acc - labels[bbase + tid];
        yerr = dv * dv * it;
        ytr  = it;
    }
    #pragma unroll
    for (int s = 8; s > 0; s >>= 1) {
        yerr += __shfl_down(yerr, s);
        ytr  += __shfl_down(ytr, s);
    }
    if (tid == 0) { wsynum[blk] = yerr; wsyden[blk] = ytr; }
}

__global__ __launch_bounds__(256) void rits_final(
    const float* __restrict__ xlpart,
    const float* __restrict__ wsynum, const float* __restrict__ wsyden,
    float* __restrict__ d_out)
{
    __shared__ float sx[256], sy[256], sz[256];
    int tid = threadIdx.x;
    sx[tid] = xlpart[tid];
    sy[tid] = wsynum[tid];
    sz[tid] = wsyden[tid];
    __syncthreads();
    for (int s = 128; s > 0; s >>= 1) {
        if (tid < s) { sx[tid] += sx[tid + s]; sy[tid] += sy[tid + s]; sz[tid] += sz[tid + s]; }
        __syncthreads();
    }
    if (tid == 0) d_out[0] = sx[0] + sy[0] / (sz[0] + 1e-5f);
}

extern "C" void kernel_launch(void* const* d_in, const int* in_sizes, int n_in,
                              void* d_out, int out_size, void* d_ws, size_t ws_size,
                              hipStream_t stream)
{
    const float* values    = (const float*)d_in[0];
    const float* masks     = (const float*)d_in[1];
    const float* deltas    = (const float*)d_in[2];
    // d_in[3] evals, d_in[4] eval_masks : unused
    const float* labels    = (const float*)d_in[5];
    const float* is_train  = (const float*)d_in[6];
    const float* W_decay   = (const float*)d_in[7];
    const float* b_decay   = (const float*)d_in[8];
    const float* W_reg     = (const float*)d_in[9];
    const float* b_reg     = (const float*)d_in[10];
    const float* W_ih      = (const float*)d_in[11];
    const float* W_hh      = (const float*)d_in[12];
    const float* b_ih      = (const float*)d_in[13];
    const float* b_hh      = (const float*)d_in[14];
    const float* W_out     = (const float*)d_in[15];
    const float* b_out     = (const float*)d_in[16];

    float* ws     = (float*)d_ws;
    float* rden   = ws + WS_RDEN;
    float* xlpart = ws + WS_XL;
    float* wsynum = ws + WS_YNUM;
    float* wsyden = ws + WS_YDEN;

    float* out     = (float*)d_out;
    float* out_yh  = out + 1;
    float* out_imp = out + 1 + BTOT;

    rits_den<<<dim3(T_LEN), dim3(1024), 0, stream>>>(masks, rden);

    rits_main<<<dim3(NB), dim3(NTHR), 0, stream>>>(
        values, masks, deltas, labels, is_train,
        W_decay, b_decay, W_reg, b_reg, W_ih, W_hh, b_ih, b_hh, W_out, b_out,
        rden, out_yh, out_imp, xlpart, wsynum, wsyden);

    rits_final<<<dim3(1), dim3(256), 0, stream>>>(xlpart, wsynum, wsyden, out);
}